// Round 1
// baseline (159.980 us; speedup 1.0000x reference)
//
#include <hip/hip_runtime.h>

#define B_  4
#define C_  256
#define C8_ 32
#define N_  4096   // H*W
#define HVS_ (N_ + 64)  // hv row stride, padded: 8192B power-of-2 stride would alias L1 sets

#define TJ 128     // j-tile per flash block
#define KI 128     // i per iteration (2 barriers per 128 i, was 3 per 64)
#define SPLITS 4   // i-range splits

typedef __attribute__((ext_vector_type(8)))  short bf16x8;   // MFMA A/B frag (8 bf16)
typedef __attribute__((ext_vector_type(16))) float f32x16;   // MFMA C/D frag

union FragAB { bf16x8 v; unsigned short u[8]; };

__device__ __forceinline__ unsigned short f2bf(float x) {
    unsigned u = __float_as_uint(x);
    unsigned r = u + 0x7FFFu + ((u >> 16) & 1u);   // RNE
    return (unsigned short)(r >> 16);
}
__device__ __forceinline__ unsigned pack2bf(float a, float b) {
    return (unsigned)f2bf(a) | ((unsigned)f2bf(b) << 16);
}
// hw packed f32->bf16 (RNE), 1 instr instead of ~8 VALU
__device__ __forceinline__ unsigned cvtpk(float lo, float hi) {
    unsigned r;
    asm("v_cvt_pk_bf16_f32 %0, %1, %2" : "=v"(r) : "v"(lo), "v"(hi));
    return r;
}

// ---------------- prep: W concat -> bf16 [320][256] ----------------
__global__ __launch_bounds__(256) void prep_w_kernel(
    const float* __restrict__ Wq, const float* __restrict__ Wk,
    const float* __restrict__ Wv, unsigned short* __restrict__ Wbf)
{
    int idx = (blockIdx.x * 256 + threadIdx.x) * 4;   // grid 80 -> 81920 elems
    int row = idx >> 8;
    int col = idx & 255;
    const float* src; int r;
    if (row < 32)      { src = Wq; r = row;      }
    else if (row < 64) { src = Wk; r = row - 32; }
    else               { src = Wv; r = row - 64; }
    float4 v = *(const float4*)&src[r * 256 + col];
    uint2 o; o.x = pack2bf(v.x, v.y); o.y = pack2bf(v.z, v.w);
    *(uint2*)&Wbf[idx] = o;
}

// ---------------- prep: x [b][c][n] fp32 -> xT [b][n][c] bf16 ----------------
__global__ __launch_bounds__(256) void prep_x_kernel(
    const float* __restrict__ x, unsigned short* __restrict__ xT)
{
    __shared__ unsigned short T[64][66];
    int t  = threadIdx.x;
    int b  = blockIdx.z;
    int c0 = blockIdx.y * 64;
    int n0 = blockIdx.x * 64;
    const float* xb = x + (size_t)b * C_ * N_;
    int n_l = t & 63, c_l = t >> 6;
#pragma unroll
    for (int q = 0; q < 16; ++q) {
        int c = c_l * 16 + q;
        T[n_l][c] = f2bf(xb[(size_t)(c0 + c) * N_ + n0 + n_l]);
    }
    __syncthreads();
    unsigned short* xTb = xT + (size_t)b * N_ * C_;
    int c_l2 = t & 63, nb = t >> 6;
#pragma unroll
    for (int q = 0; q < 16; ++q) {
        int n = nb * 16 + q;
        xTb[(size_t)(n0 + n) * C_ + c0 + c_l2] = T[n][c_l2];
    }
}

// ---------------- MFMA projection -------------------------------------------
// grid(N/32, B), 256 threads = 4 waves. Wave w: m-tiles {w, w+4, w+8(w<2)}.
// Outputs: fT [b][n][32] (k-contiguous for flash A-frags), g [b][32][N], hv [b][256][HVS_].
__global__ __launch_bounds__(256) void proj_mfma_kernel(
    const unsigned short* __restrict__ Wbf, const unsigned short* __restrict__ xT,
    unsigned short* __restrict__ fT, unsigned short* __restrict__ g,
    unsigned short* __restrict__ hv)
{
    int t = threadIdx.x, w = t >> 6, lane = t & 63;
    int half = lane >> 5, l31 = lane & 31;
    int b  = blockIdx.y;
    int n0 = blockIdx.x * 32;

    const unsigned short* xb = xT + ((size_t)b * N_ + n0 + l31) * C_;
    int nm = (w < 2) ? 3 : 2;
    int mt0 = w, mt1 = w + 4, mt2 = w + 8;

    f32x16 acc[3];
#pragma unroll
    for (int a = 0; a < 3; ++a) acc[a] = (f32x16)0.f;

#pragma unroll
    for (int ks = 0; ks < 16; ++ks) {
        int kofs = ks * 16 + half * 8;
        bf16x8 bfr = *(const bf16x8*)&xb[kofs];
        bf16x8 a0 = *(const bf16x8*)&Wbf[(size_t)(mt0 * 32 + l31) * 256 + kofs];
        acc[0] = __builtin_amdgcn_mfma_f32_32x32x16_bf16(a0, bfr, acc[0], 0, 0, 0);
        bf16x8 a1 = *(const bf16x8*)&Wbf[(size_t)(mt1 * 32 + l31) * 256 + kofs];
        acc[1] = __builtin_amdgcn_mfma_f32_32x32x16_bf16(a1, bfr, acc[1], 0, 0, 0);
        if (nm == 3) {
            bf16x8 a2 = *(const bf16x8*)&Wbf[(size_t)(mt2 * 32 + l31) * 256 + kofs];
            acc[2] = __builtin_amdgcn_mfma_f32_32x32x16_bf16(a2, bfr, acc[2], 0, 0, 0);
        }
    }

    unsigned short* fTb = fT + (size_t)b * N_ * C8_;
    unsigned short* gb  = g  + (size_t)b * C8_ * N_;
    unsigned short* hb  = hv + (size_t)b * C_  * HVS_;
#pragma unroll
    for (int im = 0; im < 3; ++im) {
        if (im >= nm) break;
        int mt = (im == 0) ? mt0 : (im == 1) ? mt1 : mt2;
        if (mt == 0) {
            // f tile -> fT[n][ch], rows R,R+1 adjacent => packed dword stores
#pragma unroll
            for (int rp = 0; rp < 8; ++rp) {
                int r = 2 * rp;
                int R = (r & 3) + 8 * (r >> 2) + 4 * half;
                unsigned u = pack2bf(acc[0][r], acc[0][r + 1]);
                *(unsigned*)&fTb[(size_t)(n0 + l31) * C8_ + R] = u;
            }
        } else {
#pragma unroll
            for (int r = 0; r < 16; ++r) {
                int R = mt * 32 + (r & 3) + 8 * (r >> 2) + 4 * half;
                unsigned short v = f2bf(acc[im][r]);
                if (R < 64) gb[(size_t)(R - 32) * N_ + n0 + l31] = v;
                else        hb[(size_t)(R - 64) * HVS_ + n0 + l31] = v;
            }
        }
    }
}

// ---------------- MFMA flash attention (direct-global operands) -------------
// 512 blocks 1-D, 4 waves. Wave w: produces scores for j-strip [w*32,w*32+32),
// consumes P for c-stripe [w*64,w*64+64). Only pT lives in LDS (XOR-swizzled).
// f and hv A-frags are loaded straight from L2 (f 256KB/b, hv 2MB/b resident);
// the old fT/hvT staging gave no reuse (each element read once) and cost a
// third barrier + staging VALU per iteration.
__global__ __launch_bounds__(256, 2) void flash_kernel(
    const unsigned short* __restrict__ fT, const unsigned short* __restrict__ g,
    const unsigned short* __restrict__ hv, unsigned short* __restrict__ o_part,
    float* __restrict__ l_part)
{
    __shared__ unsigned short pT[TJ * KI];   // [j][i] bf16, 16B-slot XOR swizzle, 32KB

    int t = threadIdx.x, w = t >> 6, lane = t & 63;
    int half = lane >> 5, l31 = lane & 31;

    // XCD-grouping decode: round-robin assigns XCD = blockIdx.x & 7, so all 32
    // j-blocks of pair p=(s,b) land on XCD p&7 -> its hv/f slice stays in that L2.
    int d  = blockIdx.x;
    int jb = (d >> 3) & 31;                    // j-block 0..31
    int p  = (d & 7) | (((d >> 8) & 1) << 3);  // pair 0..15
    int b  = p & 3;
    int s  = p >> 2;
    int j0 = jb * TJ;

    const unsigned short* fb = fT + (size_t)b * N_ * C8_;
    const unsigned short* gb = g  + (size_t)b * C8_ * N_;
    const unsigned short* hb = hv + (size_t)b * C_  * HVS_;

    FragAB gf[2];
#pragma unroll
    for (int ks = 0; ks < 2; ++ks)
#pragma unroll
        for (int r = 0; r < 8; ++r) {
            int ch = ks * 16 + half * 8 + r;
            gf[ks].u[r] = gb[(size_t)ch * N_ + j0 + w * 32 + l31];
        }

    f32x16 acc[8];   // [ct*4 + jt]
#pragma unroll
    for (int a = 0; a < 8; ++a) acc[a] = (f32x16)0.f;
    float lacc = 0.f;

    const int swz = (l31 & 15) << 4;                       // row-dependent 16B-slot XOR
    const unsigned pbase = (unsigned)(w * 32 + l31) * (KI * 2);
    char* pTc = (char*)pT;

    // per-lane hv row bases for PV (c = w*64 + ct*32 + l31)
    const unsigned short* h0 = hb + (size_t)(w * 64 + l31) * HVS_ + half * 8;
    const unsigned short* h1 = h0 + (size_t)32 * HVS_;

    int i_begin = s * (N_ / SPLITS);

    for (int ii = 0; ii < N_ / SPLITS; ii += KI) {
        int i0 = i_begin + ii;

        // ---- phase A: scores + exp -> pT (wave-private j-strip, all 128 i) ----
#pragma unroll
        for (int it = 0; it < 4; ++it) {
            const unsigned short* fr = fb + (size_t)(i0 + it * 32 + l31) * C8_ + half * 8;
            bf16x8 a0 = *(const bf16x8*)fr;          // ch 0..7   (+half*8)
            bf16x8 a1 = *(const bf16x8*)(fr + 16);   // ch 16..23 (+half*8)
            f32x16 sacc = (f32x16)0.f;
            sacc = __builtin_amdgcn_mfma_f32_32x32x16_bf16(a0, gf[0].v, sacc, 0, 0, 0);
            sacc = __builtin_amdgcn_mfma_f32_32x32x16_bf16(a1, gf[1].v, sacc, 0, 0, 0);
            float pv[16];
#pragma unroll
            for (int r = 0; r < 16; ++r) {
                pv[r] = __expf(sacc[r]);
                lacc += pv[r];
            }
#pragma unroll
            for (int a = 0; a < 4; ++a) {
                uint2 u;
                u.x = cvtpk(pv[4 * a + 0], pv[4 * a + 1]);
                u.y = cvtpk(pv[4 * a + 2], pv[4 * a + 3]);
                int ib = ((it * 64 + a * 16) ^ swz) + half * 8;
                *(uint2*)(pTc + pbase + ib) = u;
            }
        }
        __syncthreads();

        // ---- phase B: PV, A-frags direct from hv (L2), B-frags from pT ----
        const unsigned short* hp0 = h0 + i0;
        const unsigned short* hp1 = h1 + i0;
#pragma unroll
        for (int ks = 0; ks < 8; ++ks) {
            bf16x8 ah0 = *(const bf16x8*)(hp0 + ks * 16);
            bf16x8 ah1 = *(const bf16x8*)(hp1 + ks * 16);
            int ib = (ks * 32 + half * 16) ^ swz;
            bf16x8 bp[4];
#pragma unroll
            for (int jt = 0; jt < 4; ++jt)
                bp[jt] = *(const bf16x8*)(pTc + (jt * 32 + l31) * (KI * 2) + ib);
#pragma unroll
            for (int jt = 0; jt < 4; ++jt) {
                acc[jt]     = __builtin_amdgcn_mfma_f32_32x32x16_bf16(ah0, bp[jt], acc[jt], 0, 0, 0);
                acc[4 + jt] = __builtin_amdgcn_mfma_f32_32x32x16_bf16(ah1, bp[jt], acc[4 + jt], 0, 0, 0);
            }
        }
        __syncthreads();
    }

    // epilogue: o_part in bf16 (halves combine traffic); rows c,c+1 via cvt_pk + lo/hi stores
    unsigned short* ob = o_part + (size_t)(b * SPLITS + s) * C_ * N_;
#pragma unroll
    for (int ct = 0; ct < 2; ++ct)
#pragma unroll
        for (int jt = 0; jt < 4; ++jt) {
            f32x16 a = acc[ct * 4 + jt];
#pragma unroll
            for (int rp = 0; rp < 8; ++rp) {
                int r = 2 * rp;
                unsigned u = cvtpk(a[r], a[r + 1]);
                int c = w * 64 + ct * 32 + (r & 3) + 8 * (r >> 2) + 4 * half;
                size_t base = (size_t)c * N_ + j0 + jt * 32 + l31;
                ob[base]      = (unsigned short)(u & 0xffffu);
                ob[base + N_] = (unsigned short)(u >> 16);
            }
        }
    float lsum = lacc + __shfl_down(lacc, 32);
    if (lane < 32)
        l_part[(size_t)(b * SPLITS + s) * N_ + j0 + w * 32 + lane] = lsum;
}

// ---------------- combine: sum bf16 splits, normalize, residual --------------
__global__ __launch_bounds__(256) void combine_kernel(
    const unsigned short* __restrict__ o_part, const float* __restrict__ l_part,
    const float* __restrict__ x, const float* __restrict__ gamma,
    float* __restrict__ out)
{
    int j = (blockIdx.x * 256 + threadIdx.x) * 4;
    int b = blockIdx.z;
    float4 l4 = {0.f, 0.f, 0.f, 0.f};
#pragma unroll
    for (int s = 0; s < SPLITS; ++s) {
        float4 lv = *(const float4*)&l_part[(size_t)(b * SPLITS + s) * N_ + j];
        l4.x += lv.x; l4.y += lv.y; l4.z += lv.z; l4.w += lv.w;
    }
    float4 inv = {1.f / l4.x, 1.f / l4.y, 1.f / l4.z, 1.f / l4.w};
    float gm = gamma[0];
#pragma unroll
    for (int cc = 0; cc < 4; ++cc) {
        int c = blockIdx.y * 4 + cc;
        float4 o = {0.f, 0.f, 0.f, 0.f};
#pragma unroll
        for (int s = 0; s < SPLITS; ++s) {
            uint2 u = *(const uint2*)&o_part[((size_t)(b * SPLITS + s) * C_ + c) * N_ + j];
            o.x += __uint_as_float(u.x << 16);
            o.y += __uint_as_float(u.x & 0xffff0000u);
            o.z += __uint_as_float(u.y << 16);
            o.w += __uint_as_float(u.y & 0xffff0000u);
        }
        size_t idx = ((size_t)b * C_ + c) * N_ + j;
        float4 xv = *(const float4*)&x[idx];
        float4 st = {gm * o.x * inv.x + xv.x, gm * o.y * inv.y + xv.y,
                     gm * o.z * inv.z + xv.z, gm * o.w * inv.w + xv.w};
        *(float4*)&out[idx] = st;
    }
}

extern "C" void kernel_launch(void* const* d_in, const int* in_sizes, int n_in,
                              void* d_out, int out_size, void* d_ws, size_t ws_size,
                              hipStream_t stream) {
    const float* x     = (const float*)d_in[0];
    const float* Wq    = (const float*)d_in[1];
    const float* Wk    = (const float*)d_in[2];
    const float* Wv    = (const float*)d_in[3];
    const float* gamma = (const float*)d_in[4];
    float* out = (float*)d_out;

    char* ws = (char*)d_ws;
    unsigned short* o_part = (unsigned short*)ws;                          // 33.6 MB (bf16)
    float* l_part = (float*)(o_part + (size_t)SPLITS * B_ * C_ * N_);      // 256 KB
    unsigned short* fT  = (unsigned short*)(l_part + (size_t)SPLITS * B_ * N_);  // 1 MB
    unsigned short* g   = fT  + (size_t)B_ * C8_ * N_;                     // 1 MB
    unsigned short* hv  = g   + (size_t)B_ * C8_ * N_;                     // 8.5 MB (padded)
    unsigned short* Wbf = hv  + (size_t)B_ * C_  * HVS_;                   // 160 KB
    unsigned short* xT  = Wbf + (size_t)(C_ + 2 * C8_) * C_;               // 8.4 MB

    prep_w_kernel<<<dim3(80), 256, 0, stream>>>(Wq, Wk, Wv, Wbf);
    prep_x_kernel<<<dim3(N_ / 64, C_ / 64, B_), 256, 0, stream>>>(x, xT);

    proj_mfma_kernel<<<dim3(N_ / 32, B_), 256, 0, stream>>>(Wbf, xT, fT, g, hv);

    flash_kernel<<<dim3(512), 256, 0, stream>>>(fT, g, hv, o_part, l_part);

    combine_kernel<<<dim3(N_ / 1024, C_ / 4, B_), 256, 0, stream>>>(o_part, l_part, x, gamma, out);
}